// Round 8
// baseline (1059.858 us; speedup 1.0000x reference)
//
#include <hip/hip_runtime.h>
#include <math.h>

#define B_   8
#define T_   256
#define U_   64
#define UP1  65
#define DE   640
#define J_   512
#define V_   1024
#define LOG0 -1e30f

typedef __attribute__((ext_vector_type(4))) float f32x4;
typedef __attribute__((ext_vector_type(8))) int   i32x8;

__device__ __forceinline__ unsigned short f2bf(float x) {
    union { float f; unsigned int u; } c; c.f = x;
    unsigned int r = (c.u + 0x7fffu + ((c.u >> 16) & 1u)) >> 16;
    return (unsigned short)r;
}

// LDS swizzle for fp8 hB: row m (512B rows), cb = column byte offset (8B granular).
__device__ __forceinline__ unsigned hb8(unsigned m, unsigned cb) {
    return m * 512u + (cb ^ ((m & 15u) << 3));
}

// ---------------- Kernel A: C[M x 512] = A[M x 640] * W[640 x 512] (+bias) -------------
__global__ __launch_bounds__(256) void gemm_in(const float* __restrict__ A,
                                               const float* __restrict__ W,
                                               const float* __restrict__ bias,
                                               float* __restrict__ C, int M) {
    __shared__ float As[16][64];
    __shared__ float Bs[16][64];
    int tid  = threadIdx.x;
    int row0 = blockIdx.x * 64;
    int col0 = blockIdx.y * 64;
    int tx = tid & 15, ty = tid >> 4;
    float acc[4][4] = {};
    int ar  = tid >> 2;
    int akq = tid & 3;
    int bkr = tid >> 4;
    int bcq = tid & 15;
    for (int k0 = 0; k0 < DE; k0 += 16) {
        float4 av = make_float4(0.f, 0.f, 0.f, 0.f);
        int arow = row0 + ar;
        if (arow < M) av = *(const float4*)&A[arow * DE + k0 + akq * 4];
        As[akq * 4 + 0][ar] = av.x;
        As[akq * 4 + 1][ar] = av.y;
        As[akq * 4 + 2][ar] = av.z;
        As[akq * 4 + 3][ar] = av.w;
        *(float4*)&Bs[bkr][bcq * 4] = *(const float4*)&W[(k0 + bkr) * J_ + col0 + bcq * 4];
        __syncthreads();
#pragma unroll
        for (int k = 0; k < 16; ++k) {
            float4 a4 = *(const float4*)&As[k][ty * 4];
            float4 b4 = *(const float4*)&Bs[k][tx * 4];
            float a[4] = {a4.x, a4.y, a4.z, a4.w};
            float b[4] = {b4.x, b4.y, b4.z, b4.w};
#pragma unroll
            for (int i = 0; i < 4; ++i)
#pragma unroll
                for (int j = 0; j < 4; ++j) acc[i][j] += a[i] * b[j];
        }
        __syncthreads();
    }
#pragma unroll
    for (int i = 0; i < 4; ++i) {
        int row = row0 + ty * 4 + i;
        if (row >= M) continue;
#pragma unroll
        for (int j = 0; j < 4; ++j) {
            int col = col0 + tx * 4 + j;
            float v = acc[i][j];
            if (bias) v += bias[col];
            C[row * J_ + col] = v;
        }
    }
}

// ---- Kernel W: W_out[512][1024] -> K128-frag-major fp8(e4m3) Wf ----
// Wf byte layout: tl(=col>>4)*8192 + s(=k>>7)*2048 + sub(=(k>>4)&1)*1024
//                 + (lg*16+ln)*16 + (k&15), where ln=col&15, lg=(k>>5)&3.
// A wave's B-frag for (tile,s) = two coalesced 1KB loads (16B/lane each).
__global__ __launch_bounds__(256) void wt_kernel(const float* __restrict__ W,
                                                 unsigned char* __restrict__ Wf) {
    __shared__ float tile[32][33];
    int tid = threadIdx.x;
    int tx = tid & 31, ty = tid >> 5;  // 32x8
    int v0 = blockIdx.x * 32, k0 = blockIdx.y * 32;
#pragma unroll
    for (int i = 0; i < 4; ++i)
        tile[ty + i * 8][tx] = W[(size_t)(k0 + ty + i * 8) * V_ + v0 + tx];  // [k_loc][v_loc]
    __syncthreads();
    if (tid < 128) {
        int vl = tid >> 2, q = tid & 3;        // q*8 = k_loc base
        int v  = v0 + vl;
        float x[8];
#pragma unroll
        for (int j = 0; j < 8; ++j) x[j] = tile[q * 8 + j][vl];
        int lo = 0, hi = 0;
        lo = __builtin_amdgcn_cvt_pk_fp8_f32(x[0], x[1], lo, false);
        lo = __builtin_amdgcn_cvt_pk_fp8_f32(x[2], x[3], lo, true);
        hi = __builtin_amdgcn_cvt_pk_fp8_f32(x[4], x[5], hi, false);
        hi = __builtin_amdgcn_cvt_pk_fp8_f32(x[6], x[7], hi, true);
        int tl = v >> 4, ln = v & 15;
        int s  = k0 >> 7, lg = (k0 >> 5) & 3;
        *(int2*)(Wf + tl * 8192 + s * 2048 + (q >> 1) * 1024 + (lg * 16 + ln) * 16 +
                 (q & 1) * 8) = make_int2(lo, hi);
    }
}

// -------- Kernel B: MX fp8 K=128 MFMA joint. 64 cells x 1024 cols per block (8 waves) --
// wave wc owns cols [wc*128,+128): frag grid 4mi x 8ni of 16x16x128 f8f6f4 (scale=1.0).
__global__ __launch_bounds__(512, 2) void joint_mfma(const float* __restrict__ ep,
                                                     const float* __restrict__ pp,
                                                     const unsigned char* __restrict__ Wf,
                                                     const float* __restrict__ bout,
                                                     const int* __restrict__ labels,
                                                     const int* __restrict__ pblank,
                                                     float* __restrict__ blp,
                                                     float* __restrict__ llp) {
    __shared__ __align__(16) unsigned char hB[64 * 512];  // h[64][512] fp8, swizzled
    __shared__ float ps[8][64];
    __shared__ float lseA[64];

    int tid = threadIdx.x;
    int c0  = blockIdx.x * 64;

    // ---- stage h = tanh(ep+pp) as fp8 (round-6-validated) ----
    {
        int row   = tid >> 3;
        int kslot = tid & 7;
        int cell  = c0 + row;
        unsigned epRow = (unsigned)cell / 65u;
        int u = cell - (int)epRow * 65;
        int b = (int)(epRow >> 8);
        const float* epr = ep + (size_t)epRow * J_ + kslot * 64;
        const float* ppr = pp + (size_t)(b * UP1 + u) * J_ + kslot * 64;
#pragma unroll
        for (int c8 = 0; c8 < 8; ++c8) {
            float4 e0 = *(const float4*)(epr + c8 * 8);
            float4 e1 = *(const float4*)(epr + c8 * 8 + 4);
            float4 p0 = *(const float4*)(ppr + c8 * 8);
            float4 p1 = *(const float4*)(ppr + c8 * 8 + 4);
            float x[8] = {e0.x + p0.x, e0.y + p0.y, e0.z + p0.z, e0.w + p0.w,
                          e1.x + p1.x, e1.y + p1.y, e1.z + p1.z, e1.w + p1.w};
            float t[8];
#pragma unroll
            for (int j = 0; j < 8; ++j) {
                float e2 = __expf(2.f * x[j]);
                t[j] = 1.f - 2.f / (e2 + 1.f);
            }
            int lo = 0, hi = 0;
            lo = __builtin_amdgcn_cvt_pk_fp8_f32(t[0], t[1], lo, false);
            lo = __builtin_amdgcn_cvt_pk_fp8_f32(t[2], t[3], lo, true);
            hi = __builtin_amdgcn_cvt_pk_fp8_f32(t[4], t[5], hi, false);
            hi = __builtin_amdgcn_cvt_pk_fp8_f32(t[6], t[7], hi, true);
            unsigned cb = (unsigned)(kslot * 64 + c8 * 8);
            *(int2*)(hB + hb8((unsigned)row, cb)) = make_int2(lo, hi);
        }
    }
    __syncthreads();

    int wc = tid >> 6, lane = tid & 63;
    int lg = lane >> 4, ln = lane & 15;

    f32x4 acc[4][8] = {};

    const char* wfB = (const char*)Wf + (wc << 16) + lane * 16;

    union BF { int4 q[2]; i32x8 v; };
    union AF { long l[4]; i32x8 v; };
    BF bfa[4], bfb[4];
    AF af[4];

    // prologue: group-0 B-frags of s=0
#pragma unroll
    for (int n2 = 0; n2 < 4; ++n2) {
        const char* p = wfB + n2 * 8192;
        bfa[n2].q[0] = *(const int4*)p;
        bfa[n2].q[1] = *(const int4*)(p + 1024);
    }

#pragma unroll
    for (int s = 0; s < 4; ++s) {
        // A-frags for this K128 step (16x 8B swizzled LDS reads)
#pragma unroll
        for (int mi = 0; mi < 4; ++mi) {
            unsigned m  = (unsigned)(mi * 16 + ln);
            unsigned cb = (unsigned)(s * 128 + lg * 32);
            af[mi].l[0] = *(const long*)(hB + hb8(m, cb));
            af[mi].l[1] = *(const long*)(hB + hb8(m, cb + 8));
            af[mi].l[2] = *(const long*)(hB + hb8(m, cb + 16));
            af[mi].l[3] = *(const long*)(hB + hb8(m, cb + 24));
        }
        // issue group-1 loads for s
#pragma unroll
        for (int n2 = 0; n2 < 4; ++n2) {
            const char* p = wfB + (n2 + 4) * 8192 + s * 2048;
            bfb[n2].q[0] = *(const int4*)p;
            bfb[n2].q[1] = *(const int4*)(p + 1024);
        }
        __builtin_amdgcn_s_setprio(1);
#pragma unroll
        for (int mi = 0; mi < 4; ++mi)
#pragma unroll
            for (int n2 = 0; n2 < 4; ++n2)
                acc[mi][n2] = __builtin_amdgcn_mfma_scale_f32_16x16x128_f8f6f4(
                    af[mi].v, bfa[n2].v, acc[mi][n2], 0, 0, 0, 0x7F7F7F7F, 0, 0x7F7F7F7F);
        __builtin_amdgcn_s_setprio(0);
        if (s < 3) {
#pragma unroll
            for (int n2 = 0; n2 < 4; ++n2) {
                const char* p = wfB + n2 * 8192 + (s + 1) * 2048;
                bfa[n2].q[0] = *(const int4*)p;
                bfa[n2].q[1] = *(const int4*)(p + 1024);
            }
        }
        __builtin_amdgcn_s_setprio(1);
#pragma unroll
        for (int mi = 0; mi < 4; ++mi)
#pragma unroll
            for (int n2 = 0; n2 < 4; ++n2)
                acc[mi][n2 + 4] = __builtin_amdgcn_mfma_scale_f32_16x16x128_f8f6f4(
                    af[mi].v, bfb[n2].v, acc[mi][n2 + 4], 0, 0, 0, 0x7F7F7F7F, 0, 0x7F7F7F7F);
        __builtin_amdgcn_s_setprio(0);
    }

    // ---- epilogue: bias, exp-sum (|logits| small: no max needed), lse, gather ----
    float bo[8];
#pragma unroll
    for (int ni = 0; ni < 8; ++ni) bo[ni] = bout[(wc << 7) + (ni << 4) + ln];
#pragma unroll
    for (int mi = 0; mi < 4; ++mi)
#pragma unroll
        for (int ni = 0; ni < 8; ++ni)
#pragma unroll
            for (int r = 0; r < 4; ++r) acc[mi][ni][r] += bo[ni];

#pragma unroll
    for (int mi = 0; mi < 4; ++mi) {
#pragma unroll
        for (int r = 0; r < 4; ++r) {
            float s = 0.f;
#pragma unroll
            for (int ni = 0; ni < 8; ++ni) s += __expf(acc[mi][ni][r]);
            s += __shfl_xor(s, 1);
            s += __shfl_xor(s, 2);
            s += __shfl_xor(s, 4);
            s += __shfl_xor(s, 8);
            if (ln == 0) ps[wc][mi * 16 + lg * 4 + r] = s;
        }
    }
    __syncthreads();
    if (tid < 64) {
        float S = 0.f;
#pragma unroll
        for (int w2 = 0; w2 < 8; ++w2) S += ps[w2][tid];
        lseA[tid] = __logf(S);
    }
    __syncthreads();

    int blank = *pblank;
#pragma unroll
    for (int mi = 0; mi < 4; ++mi) {
#pragma unroll
        for (int r = 0; r < 4; ++r) {
            int row  = mi * 16 + lg * 4 + r;
            int cell = c0 + row;
            unsigned epRow = (unsigned)cell / 65u;
            int u = cell - (int)epRow * 65;
            int b = (int)(epRow >> 8);
            int lab = (u < U_) ? labels[(b << 6) + u] : -1;
            float lse = lseA[row];
#pragma unroll
            for (int ni = 0; ni < 8; ++ni) {
                int col  = (wc << 7) + (ni << 4) + ln;
                float lp = acc[mi][ni][r] - lse;
                if (col == blank) blp[cell] = lp;
                if (col == lab)   llp[(size_t)(((int)epRow << 6) + u)] = lp;
            }
        }
    }
}

// ------- Kernel C: alpha scan, log2-domain, prefix-sum-of-exp2 (1 exp + 1 log per t) ---
__global__ __launch_bounds__(512) void scan_kernel(const float* __restrict__ blp,
                                                   const float* __restrict__ llp,
                                                   const int* __restrict__ enc_lens,
                                                   const int* __restrict__ label_lens,
                                                   float* __restrict__ out) {
    __shared__ float lossArr[B_];
    const float K2  = 1.4426950408889634f;   // log2(e)
    const float LN2 = 0.6931471805599453f;
    int tid  = threadIdx.x;
    int b    = tid >> 6;
    int lane = tid & 63;
    int el = enc_lens[b];
    int ll = label_lens[b];
    float alpha   = (lane == 0) ? 0.f : LOG0;  // log2-domain (0 / -1e30 invariant)
    float alpha64 = LOG0;                      // uniform across lanes
    const float* bb = &blp[(size_t)b * T_ * UP1];
    const float* lb = &llp[(size_t)b * T_ * U_];

    for (int t = 0; t < T_; ++t) {
        float bv   = bb[t * UP1 + lane] * K2;
        float bv64 = bb[t * UP1 + 64] * K2;
        float lv   = lb[t * U_ + lane] * K2;
        // inclusive prefix sum of label log2-probs
        float P = lv;
#pragma unroll
        for (int d = 1; d < 64; d <<= 1) {
            float v = __shfl(P, lane - d);
            if (lane >= d) P += v;
        }
        float L = __shfl(P, lane - 1);
        if (lane == 0) L = 0.f;
        float P63 = __shfl(P, 63);
        float x   = alpha + bv - L;
        float x64 = alpha64 + bv64 - P63;      // uniform
        // global max (cheap fmax butterfly; no transcendentals)
        float M = x;
#pragma unroll
        for (int d = 1; d < 64; d <<= 1) M = fmaxf(M, __shfl_xor(M, d));
        M = fmaxf(M, x64);
        // one exp2, plain add-scan, one log2
        float S = __builtin_amdgcn_exp2f(x - M);
#pragma unroll
        for (int d = 1; d < 64; d <<= 1) {
            float v = __shfl(S, lane - d);
            if (lane >= d) S += v;
        }
        float S63 = __shfl(S, 63);
        float anew   = L + M + __builtin_amdgcn_logf(S);
        float anew64 = P63 + M + __builtin_amdgcn_logf(S63 + __builtin_amdgcn_exp2f(x64 - M));
        if (t < el) {  // wave-uniform
            alpha   = anew;
            alpha64 = anew64;
        }
    }

    float term = bb[(el - 1) * UP1 + ll] * K2;
    int li = (ll < 64) ? ll : 63;
    float aU = __shfl(alpha, li);
    if (ll >= 64) aU = alpha64;
    if (lane == 0) lossArr[b] = -(aU + term) * LN2;
    __syncthreads();
    if (tid == 0) {
        float s = 0.f;
        for (int i = 0; i < B_; ++i) s += lossArr[i];
        out[0] = s / (float)B_;
    }
}

extern "C" void kernel_launch(void* const* d_in, const int* in_sizes, int n_in,
                              void* d_out, int out_size, void* d_ws, size_t ws_size,
                              hipStream_t stream) {
    (void)in_sizes; (void)n_in; (void)out_size; (void)ws_size;
    const float* enc        = (const float*)d_in[0];
    const float* pred       = (const float*)d_in[1];
    const float* W_enc      = (const float*)d_in[2];
    const float* W_pred     = (const float*)d_in[3];
    const float* b_joint    = (const float*)d_in[4];
    const float* W_out      = (const float*)d_in[5];
    const float* b_out      = (const float*)d_in[6];
    const int*   labels     = (const int*)d_in[7];
    const int*   enc_lens   = (const int*)d_in[8];
    const int*   label_lens = (const int*)d_in[9];
    const int*   blank_id   = (const int*)d_in[10];

    float* ep  = (float*)d_ws;                      // B*T*J   = 1,048,576 f
    float* pp  = ep  + (size_t)B_ * T_ * J_;        // B*65*J  =   266,240 f
    float* blp = pp  + (size_t)B_ * UP1 * J_;       // B*T*65  =   133,120 f
    float* llp = blp + (size_t)B_ * T_ * UP1;       // B*T*64  =   131,072 f
    unsigned char* Wf = (unsigned char*)(llp + (size_t)B_ * T_ * U_);  // 512KB frag-major fp8

    wt_kernel<<<dim3(V_ / 32, J_ / 32), dim3(256), 0, stream>>>(W_out, Wf);
    gemm_in<<<dim3((B_ * T_ + 63) / 64, J_ / 64), dim3(256), 0, stream>>>(
        enc, W_enc, b_joint, ep, B_ * T_);
    gemm_in<<<dim3((B_ * UP1 + 63) / 64, J_ / 64), dim3(256), 0, stream>>>(
        pred, W_pred, nullptr, pp, B_ * UP1);
    joint_mfma<<<dim3(B_ * T_ * UP1 / 64), dim3(512), 0, stream>>>(
        ep, pp, Wf, b_out, labels, blank_id, blp, llp);
    scan_kernel<<<dim3(1), dim3(512), 0, stream>>>(blp, llp, enc_lens, label_lens,
                                                   (float*)d_out);
}

// Round 9
// 503.285 us; speedup vs baseline: 2.1059x; 2.1059x over previous
//
#include <hip/hip_runtime.h>
#include <math.h>

#define B_   8
#define T_   256
#define U_   64
#define UP1  65
#define DE   640
#define J_   512
#define V_   1024
#define NCELL (B_ * T_ * UP1)
#define LOG0 -1e30f

typedef __attribute__((ext_vector_type(4))) float f32x4;

// ---------------- DPP wave64 scan/reduce helpers (LLVM atomic-optimizer pattern) -------
template<int CTRL, int RM>
__device__ __forceinline__ float dppz(float x) {  // masked/invalid lanes contribute 0
    return __builtin_bit_cast(float,
        __builtin_amdgcn_update_dpp(0, __builtin_bit_cast(int, x), CTRL, RM, 0xf, false));
}
template<int CTRL, int RM>
__device__ __forceinline__ float dpps(float x) {  // masked/invalid lanes keep self
    int xi = __builtin_bit_cast(int, x);
    return __builtin_bit_cast(float,
        __builtin_amdgcn_update_dpp(xi, xi, CTRL, RM, 0xf, false));
}
__device__ __forceinline__ float wave_prefix_sum(float v) {
    v += dppz<0x111, 0xf>(v);
    v += dppz<0x112, 0xf>(v);
    v += dppz<0x114, 0xf>(v);
    v += dppz<0x118, 0xf>(v);
    v += dppz<0x142, 0xa>(v);   // row_bcast15 -> rows 1,3
    v += dppz<0x143, 0xc>(v);   // row_bcast31 -> rows 2,3
    return v;
}
__device__ __forceinline__ float wave_max_all(float v) {
    v = fmaxf(v, dpps<0x111, 0xf>(v));
    v = fmaxf(v, dpps<0x112, 0xf>(v));
    v = fmaxf(v, dpps<0x114, 0xf>(v));
    v = fmaxf(v, dpps<0x118, 0xf>(v));
    v = fmaxf(v, dpps<0x142, 0xa>(v));
    v = fmaxf(v, dpps<0x143, 0xc>(v));
    return __builtin_bit_cast(float,
        __builtin_amdgcn_readlane(__builtin_bit_cast(int, v), 63));
}
__device__ __forceinline__ float rdlane(float v, int l) {
    return __builtin_bit_cast(float,
        __builtin_amdgcn_readlane(__builtin_bit_cast(int, v), l));
}

// LDS swizzle for fp8 hB: row m (512B rows), cb = column byte offset (8B granular).
__device__ __forceinline__ unsigned hb8(unsigned m, unsigned cb) {
    return m * 512u + (cb ^ ((m & 15u) << 3));
}

// ---------------- Kernel A: C[M x 512] = A[M x 640] * W[640 x 512] (+bias) -------------
__global__ __launch_bounds__(256) void gemm_in(const float* __restrict__ A,
                                               const float* __restrict__ W,
                                               const float* __restrict__ bias,
                                               float* __restrict__ C, int M) {
    __shared__ float As[16][64];
    __shared__ float Bs[16][64];
    int tid  = threadIdx.x;
    int row0 = blockIdx.x * 64;
    int col0 = blockIdx.y * 64;
    int tx = tid & 15, ty = tid >> 4;
    float acc[4][4] = {};
    int ar  = tid >> 2;
    int akq = tid & 3;
    int bkr = tid >> 4;
    int bcq = tid & 15;
    for (int k0 = 0; k0 < DE; k0 += 16) {
        float4 av = make_float4(0.f, 0.f, 0.f, 0.f);
        int arow = row0 + ar;
        if (arow < M) av = *(const float4*)&A[arow * DE + k0 + akq * 4];
        As[akq * 4 + 0][ar] = av.x;
        As[akq * 4 + 1][ar] = av.y;
        As[akq * 4 + 2][ar] = av.z;
        As[akq * 4 + 3][ar] = av.w;
        *(float4*)&Bs[bkr][bcq * 4] = *(const float4*)&W[(k0 + bkr) * J_ + col0 + bcq * 4];
        __syncthreads();
#pragma unroll
        for (int k = 0; k < 16; ++k) {
            float4 a4 = *(const float4*)&As[k][ty * 4];
            float4 b4 = *(const float4*)&Bs[k][tx * 4];
            float a[4] = {a4.x, a4.y, a4.z, a4.w};
            float b[4] = {b4.x, b4.y, b4.z, b4.w};
#pragma unroll
            for (int i = 0; i < 4; ++i)
#pragma unroll
                for (int j = 0; j < 4; ++j) acc[i][j] += a[i] * b[j];
        }
        __syncthreads();
    }
#pragma unroll
    for (int i = 0; i < 4; ++i) {
        int row = row0 + ty * 4 + i;
        if (row >= M) continue;
#pragma unroll
        for (int j = 0; j < 4; ++j) {
            int col = col0 + tx * 4 + j;
            float v = acc[i][j];
            if (bias) v += bias[col];
            C[row * J_ + col] = v;
        }
    }
}

// ---- Kernel W: W_out[512][1024] -> fragment-major fp8(e4m3) Wf (round-6 layout) ----
__global__ __launch_bounds__(256) void wt_kernel(const float* __restrict__ W,
                                                 unsigned char* __restrict__ Wf) {
    __shared__ float tile[32][33];
    int tid = threadIdx.x;
    int tx = tid & 31, ty = tid >> 5;  // 32x8
    int v0 = blockIdx.x * 32, k0 = blockIdx.y * 32;
#pragma unroll
    for (int i = 0; i < 4; ++i)
        tile[ty + i * 8][tx] = W[(size_t)(k0 + ty + i * 8) * V_ + v0 + tx];  // [k_loc][v_loc]
    __syncthreads();
    if (tid < 128) {
        int vl = tid >> 2, lg = tid & 3;
        int v  = v0 + vl;
        float x[8];
#pragma unroll
        for (int j = 0; j < 8; ++j) x[j] = tile[lg * 8 + j][vl];
        int lo = 0, hi = 0;
        lo = __builtin_amdgcn_cvt_pk_fp8_f32(x[0], x[1], lo, false);
        lo = __builtin_amdgcn_cvt_pk_fp8_f32(x[2], x[3], lo, true);
        hi = __builtin_amdgcn_cvt_pk_fp8_f32(x[4], x[5], hi, false);
        hi = __builtin_amdgcn_cvt_pk_fp8_f32(x[6], x[7], hi, true);
        int tl = v >> 4, ln = v & 15, kt = k0 >> 5;
        *(int2*)(Wf + tl * 8192 + kt * 512 + (lg * 16 + ln) * 8) = make_int2(lo, hi);
    }
}

// ---- Kernel B: fp8 MFMA joint, col-split. Block = 64 cells x 512 cols (8 waves). -----
// blockIdx: bx>>1 = cell tile, bx&1 = column half. Wave wc: cols bh*512 + wc*64 .. +64.
// acc[4][4] = 64 AGPR -> ~150 regs/wave -> 3 waves/SIMD, 3 blocks/CU.
__global__ __launch_bounds__(512, 3) void joint_mfma(const float* __restrict__ ep,
                                                     const float* __restrict__ pp,
                                                     const unsigned char* __restrict__ Wf,
                                                     const float* __restrict__ bout,
                                                     const int* __restrict__ labels,
                                                     const int* __restrict__ pblank,
                                                     float* __restrict__ Spart,
                                                     float* __restrict__ blp,
                                                     float* __restrict__ llp) {
    __shared__ __align__(16) unsigned char hB[64 * 512];  // h[64][512] fp8, swizzled
    __shared__ float ps[8][64];

    int tid = threadIdx.x;
    int bx  = blockIdx.x;
    int c0  = (bx >> 1) * 64;
    int bh  = bx & 1;

    // ---- stage h = tanh(ep+pp) as fp8 (round-6-validated; duplicated across halves) ----
    {
        int row   = tid >> 3;
        int kslot = tid & 7;
        int cell  = c0 + row;
        unsigned epRow = (unsigned)cell / 65u;
        int u = cell - (int)epRow * 65;
        int b = (int)(epRow >> 8);
        const float* epr = ep + (size_t)epRow * J_ + kslot * 64;
        const float* ppr = pp + (size_t)(b * UP1 + u) * J_ + kslot * 64;
#pragma unroll
        for (int c8 = 0; c8 < 8; ++c8) {
            float4 e0 = *(const float4*)(epr + c8 * 8);
            float4 e1 = *(const float4*)(epr + c8 * 8 + 4);
            float4 p0 = *(const float4*)(ppr + c8 * 8);
            float4 p1 = *(const float4*)(ppr + c8 * 8 + 4);
            float x[8] = {e0.x + p0.x, e0.y + p0.y, e0.z + p0.z, e0.w + p0.w,
                          e1.x + p1.x, e1.y + p1.y, e1.z + p1.z, e1.w + p1.w};
            float t[8];
#pragma unroll
            for (int j = 0; j < 8; ++j) {
                float e2 = __expf(2.f * x[j]);
                t[j] = 1.f - 2.f / (e2 + 1.f);
            }
            int lo = 0, hi = 0;
            lo = __builtin_amdgcn_cvt_pk_fp8_f32(t[0], t[1], lo, false);
            lo = __builtin_amdgcn_cvt_pk_fp8_f32(t[2], t[3], lo, true);
            hi = __builtin_amdgcn_cvt_pk_fp8_f32(t[4], t[5], hi, false);
            hi = __builtin_amdgcn_cvt_pk_fp8_f32(t[6], t[7], hi, true);
            unsigned cb = (unsigned)(kslot * 64 + c8 * 8);
            *(int2*)(hB + hb8((unsigned)row, cb)) = make_int2(lo, hi);
        }
    }
    __syncthreads();

    int wc = tid >> 6, lane = tid & 63;
    int lg = lane >> 4, ln = lane & 15;

    f32x4 acc[4][4] = {};

    // frag-major Wf as longs: tile index bh*32 + wc*4 + ni; elem = tile*1024 + kt*64 + lane
    const long* wfbL = (const long*)Wf + (((bh << 5) + (wc << 2)) << 10) + lane;

    long bf[3][4];
    long af[2][4];
#pragma unroll
    for (int ni = 0; ni < 4; ++ni) bf[0][ni] = wfbL[ni * 1024];
#pragma unroll
    for (int ni = 0; ni < 4; ++ni) bf[1][ni] = wfbL[ni * 1024 + 64];
#pragma unroll
    for (int mi = 0; mi < 4; ++mi) {
        unsigned m  = (unsigned)(mi * 16 + ln);
        unsigned cb = (unsigned)(lg * 8);
        af[0][mi] = *(const long*)(hB + hb8(m, cb));
    }

#pragma unroll
    for (int kt = 0; kt < 16; ++kt) {
        const int cur3 = kt % 3;
        const int pf3  = (kt + 2) % 3;
        const int cur  = kt & 1, nxt = cur ^ 1;
#pragma unroll
        for (int ni = 0; ni < 4; ++ni) {
            if (kt < 14) bf[pf3][ni] = wfbL[ni * 1024 + (kt + 2) * 64];
            __builtin_amdgcn_s_setprio(1);
#pragma unroll
            for (int mi = 0; mi < 4; ++mi)
                acc[mi][ni] = __builtin_amdgcn_mfma_f32_16x16x32_fp8_fp8(
                    af[cur][mi], bf[cur3][ni], acc[mi][ni], 0, 0, 0);
            __builtin_amdgcn_s_setprio(0);
            if (ni == 1 && kt < 15) {
#pragma unroll
                for (int mi = 0; mi < 4; ++mi) {
                    unsigned m  = (unsigned)(mi * 16 + ln);
                    unsigned cb = (unsigned)((kt + 1) * 32 + lg * 8);
                    af[nxt][mi] = *(const long*)(hB + hb8(m, cb));
                }
            }
        }
    }

    // ---- epilogue: bias, partial exp-sum over this half's 512 cols, raw-logit gather ---
    float bo[4];
#pragma unroll
    for (int ni = 0; ni < 4; ++ni) bo[ni] = bout[(bh << 9) + (wc << 6) + (ni << 4) + ln];
#pragma unroll
    for (int mi = 0; mi < 4; ++mi)
#pragma unroll
        for (int ni = 0; ni < 4; ++ni)
#pragma unroll
            for (int r = 0; r < 4; ++r) acc[mi][ni][r] += bo[ni];

#pragma unroll
    for (int mi = 0; mi < 4; ++mi) {
#pragma unroll
        for (int r = 0; r < 4; ++r) {
            float s = 0.f;
#pragma unroll
            for (int ni = 0; ni < 4; ++ni) s += __expf(acc[mi][ni][r]);
            s += __shfl_xor(s, 1);
            s += __shfl_xor(s, 2);
            s += __shfl_xor(s, 4);
            s += __shfl_xor(s, 8);
            if (ln == 0) ps[wc][mi * 16 + lg * 4 + r] = s;
        }
    }
    __syncthreads();
    if (tid < 64) {
        float S = 0.f;
#pragma unroll
        for (int w2 = 0; w2 < 8; ++w2) S += ps[w2][tid];
        Spart[(size_t)bh * NCELL + c0 + tid] = S;
    }

    int blank = *pblank;
#pragma unroll
    for (int mi = 0; mi < 4; ++mi) {
#pragma unroll
        for (int r = 0; r < 4; ++r) {
            int row  = mi * 16 + lg * 4 + r;
            int cell = c0 + row;
            unsigned epRow = (unsigned)cell / 65u;
            int u = cell - (int)epRow * 65;
            int b = (int)(epRow >> 8);
            int lab = (u < U_) ? labels[(b << 6) + u] : -1;
#pragma unroll
            for (int ni = 0; ni < 4; ++ni) {
                int col = (bh << 9) + (wc << 6) + (ni << 4) + ln;
                float lg_ = acc[mi][ni][r];
                if (col == blank) blp[cell] = lg_;                       // raw
                if (col == lab)   llp[(size_t)(((int)epRow << 6) + u)] = lg_;  // raw
            }
        }
    }
}

// ---- Pass 2: lse = log(S0+S1); subtract from raw blank/label logits ----
__global__ __launch_bounds__(256) void pass2_kernel(const float* __restrict__ Spart,
                                                    float* __restrict__ blp,
                                                    float* __restrict__ llp) {
    int idx = blockIdx.x * 256 + threadIdx.x;
    if (idx >= NCELL) return;
    float lse = __logf(Spart[idx] + Spart[NCELL + idx]);
    blp[idx] -= lse;
    unsigned epRow = (unsigned)idx / 65u;
    int u = idx - (int)epRow * 65;
    if (u < U_) llp[(size_t)((epRow << 6) + u)] -= lse;
}

// ------- Kernel C: alpha scan, log2-domain, DPP scans + prefetched loads ---------------
__global__ __launch_bounds__(512) void scan_kernel(const float* __restrict__ blp,
                                                   const float* __restrict__ llp,
                                                   const int* __restrict__ enc_lens,
                                                   const int* __restrict__ label_lens,
                                                   float* __restrict__ out) {
    __shared__ float lossArr[B_];
    const float K2  = 1.4426950408889634f;   // log2(e)
    const float LN2 = 0.6931471805599453f;
    int tid  = threadIdx.x;
    int b    = tid >> 6;
    int lane = tid & 63;
    int el = enc_lens[b];
    int ll = label_lens[b];
    float alpha   = (lane == 0) ? 0.f : LOG0;  // log2-domain
    float alpha64 = LOG0;
    const float* bb = &blp[(size_t)b * T_ * UP1];
    const float* lb = &llp[(size_t)b * T_ * U_];

    float bv_n   = bb[lane] * K2;
    float bv64_n = bb[64] * K2;
    float lv_n   = lb[lane] * K2;

    for (int t = 0; t < T_; ++t) {
        float bv = bv_n, bv64 = bv64_n, lv = lv_n;
        if (t + 1 < T_) {                       // prefetch next t (off critical chain)
            bv_n   = bb[(t + 1) * UP1 + lane] * K2;
            bv64_n = bb[(t + 1) * UP1 + 64] * K2;
            lv_n   = lb[(t + 1) * U_ + lane] * K2;
        }
        // inclusive prefix sum of label log2-probs (DPP)
        float P = wave_prefix_sum(lv);
        // exclusive prefix L: shift by one lane (DPP row_shr:1 + patch lanes 0,16,32,48)
        float L = dpps<0x111, 0xf>(P);
        float P15 = rdlane(P, 15), P31 = rdlane(P, 31), P47 = rdlane(P, 47);
        if (lane == 0)  L = 0.f;
        if (lane == 16) L = P15;
        if (lane == 32) L = P31;
        if (lane == 48) L = P47;
        float P63 = rdlane(P, 63);
        float x   = alpha + bv - L;
        float x64 = alpha64 + bv64 - P63;
        float M = fmaxf(wave_max_all(x), x64);
        float S = wave_prefix_sum(__builtin_amdgcn_exp2f(x - M));
        float S63 = rdlane(S, 63);
        float anew   = L + M + __builtin_amdgcn_logf(S);
        float anew64 = P63 + M +
                       __builtin_amdgcn_logf(S63 + __builtin_amdgcn_exp2f(x64 - M));
        if (t < el) {  // wave-uniform
            alpha   = anew;
            alpha64 = anew64;
        }
    }

    float term = bb[(el - 1) * UP1 + ll] * K2;
    int li = (ll < 64) ? ll : 63;
    float aU = __shfl(alpha, li);
    if (ll >= 64) aU = alpha64;
    if (lane == 0) lossArr[b] = -(aU + term) * LN2;
    __syncthreads();
    if (tid == 0) {
        float s = 0.f;
        for (int i = 0; i < B_; ++i) s += lossArr[i];
        out[0] = s / (float)B_;
    }
}

extern "C" void kernel_launch(void* const* d_in, const int* in_sizes, int n_in,
                              void* d_out, int out_size, void* d_ws, size_t ws_size,
                              hipStream_t stream) {
    (void)in_sizes; (void)n_in; (void)out_size; (void)ws_size;
    const float* enc        = (const float*)d_in[0];
    const float* pred       = (const float*)d_in[1];
    const float* W_enc      = (const float*)d_in[2];
    const float* W_pred     = (const float*)d_in[3];
    const float* b_joint    = (const float*)d_in[4];
    const float* W_out      = (const float*)d_in[5];
    const float* b_out      = (const float*)d_in[6];
    const int*   labels     = (const int*)d_in[7];
    const int*   enc_lens   = (const int*)d_in[8];
    const int*   label_lens = (const int*)d_in[9];
    const int*   blank_id   = (const int*)d_in[10];

    float* ep  = (float*)d_ws;                      // B*T*J   = 1,048,576 f
    float* pp  = ep  + (size_t)B_ * T_ * J_;        // B*65*J  =   266,240 f
    float* blp = pp  + (size_t)B_ * UP1 * J_;       // B*T*65  =   133,120 f
    float* llp = blp + (size_t)B_ * T_ * UP1;       // B*T*64  =   131,072 f
    unsigned char* Wf = (unsigned char*)(llp + (size_t)B_ * T_ * U_);  // 512KB frag fp8
    float* Spart = (float*)(Wf + (size_t)V_ * J_);  // 2 * NCELL f32

    wt_kernel<<<dim3(V_ / 32, J_ / 32), dim3(256), 0, stream>>>(W_out, Wf);
    gemm_in<<<dim3((B_ * T_ + 63) / 64, J_ / 64), dim3(256), 0, stream>>>(
        enc, W_enc, b_joint, ep, B_ * T_);
    gemm_in<<<dim3((B_ * UP1 + 63) / 64, J_ / 64), dim3(256), 0, stream>>>(
        pred, W_pred, nullptr, pp, B_ * UP1);
    joint_mfma<<<dim3(NCELL / 64 * 2), dim3(512), 0, stream>>>(
        ep, pp, Wf, b_out, labels, blank_id, Spart, blp, llp);
    pass2_kernel<<<dim3((NCELL + 255) / 256), dim3(256), 0, stream>>>(Spart, blp, llp);
    scan_kernel<<<dim3(1), dim3(512), 0, stream>>>(blp, llp, enc_lens, label_lens,
                                                   (float*)d_out);
}

// Round 10
// 442.190 us; speedup vs baseline: 2.3968x; 1.1382x over previous
//
#include <hip/hip_runtime.h>
#include <math.h>

#define B_   8
#define T_   256
#define U_   64
#define UP1  65
#define DE   640
#define J_   512
#define V_   1024
#define NCELL (B_ * T_ * UP1)
#define LOG0 -1e30f

typedef __attribute__((ext_vector_type(4))) float f32x4;

// ---------------- DPP wave64 scan/reduce helpers -------------------------------------
template<int CTRL, int RM>
__device__ __forceinline__ float dppz(float x) {  // masked/invalid lanes contribute 0
    return __builtin_bit_cast(float,
        __builtin_amdgcn_update_dpp(0, __builtin_bit_cast(int, x), CTRL, RM, 0xf, false));
}
template<int CTRL, int RM>
__device__ __forceinline__ float dpps(float x) {  // masked/invalid lanes keep self
    int xi = __builtin_bit_cast(int, x);
    return __builtin_bit_cast(float,
        __builtin_amdgcn_update_dpp(xi, xi, CTRL, RM, 0xf, false));
}
__device__ __forceinline__ float wave_prefix_sum(float v) {
    v += dppz<0x111, 0xf>(v);
    v += dppz<0x112, 0xf>(v);
    v += dppz<0x114, 0xf>(v);
    v += dppz<0x118, 0xf>(v);
    v += dppz<0x142, 0xa>(v);   // row_bcast15 -> rows 1,3
    v += dppz<0x143, 0xc>(v);   // row_bcast31 -> rows 2,3
    return v;
}
__device__ __forceinline__ float wave_max_all(float v) {
    v = fmaxf(v, dpps<0x111, 0xf>(v));
    v = fmaxf(v, dpps<0x112, 0xf>(v));
    v = fmaxf(v, dpps<0x114, 0xf>(v));
    v = fmaxf(v, dpps<0x118, 0xf>(v));
    v = fmaxf(v, dpps<0x142, 0xa>(v));
    v = fmaxf(v, dpps<0x143, 0xc>(v));
    return __builtin_bit_cast(float,
        __builtin_amdgcn_readlane(__builtin_bit_cast(int, v), 63));
}
__device__ __forceinline__ float rdlane(float v, int l) {
    return __builtin_bit_cast(float,
        __builtin_amdgcn_readlane(__builtin_bit_cast(int, v), l));
}

// LDS swizzle for fp8 hB: row m (512B rows), cb = column byte offset (8B granular).
__device__ __forceinline__ unsigned hb8(unsigned m, unsigned cb) {
    return m * 512u + (cb ^ ((m & 15u) << 3));
}

// ---------------- Kernel A: C[M x 512] = A[M x 640] * W[640 x 512] (+bias) -------------
__global__ __launch_bounds__(256) void gemm_in(const float* __restrict__ A,
                                               const float* __restrict__ W,
                                               const float* __restrict__ bias,
                                               float* __restrict__ C, int M) {
    __shared__ float As[16][64];
    __shared__ float Bs[16][64];
    int tid  = threadIdx.x;
    int row0 = blockIdx.x * 64;
    int col0 = blockIdx.y * 64;
    int tx = tid & 15, ty = tid >> 4;
    float acc[4][4] = {};
    int ar  = tid >> 2;
    int akq = tid & 3;
    int bkr = tid >> 4;
    int bcq = tid & 15;
    for (int k0 = 0; k0 < DE; k0 += 16) {
        float4 av = make_float4(0.f, 0.f, 0.f, 0.f);
        int arow = row0 + ar;
        if (arow < M) av = *(const float4*)&A[arow * DE + k0 + akq * 4];
        As[akq * 4 + 0][ar] = av.x;
        As[akq * 4 + 1][ar] = av.y;
        As[akq * 4 + 2][ar] = av.z;
        As[akq * 4 + 3][ar] = av.w;
        *(float4*)&Bs[bkr][bcq * 4] = *(const float4*)&W[(k0 + bkr) * J_ + col0 + bcq * 4];
        __syncthreads();
#pragma unroll
        for (int k = 0; k < 16; ++k) {
            float4 a4 = *(const float4*)&As[k][ty * 4];
            float4 b4 = *(const float4*)&Bs[k][tx * 4];
            float a[4] = {a4.x, a4.y, a4.z, a4.w};
            float b[4] = {b4.x, b4.y, b4.z, b4.w};
#pragma unroll
            for (int i = 0; i < 4; ++i)
#pragma unroll
                for (int j = 0; j < 4; ++j) acc[i][j] += a[i] * b[j];
        }
        __syncthreads();
    }
#pragma unroll
    for (int i = 0; i < 4; ++i) {
        int row = row0 + ty * 4 + i;
        if (row >= M) continue;
#pragma unroll
        for (int j = 0; j < 4; ++j) {
            int col = col0 + tx * 4 + j;
            float v = acc[i][j];
            if (bias) v += bias[col];
            C[row * J_ + col] = v;
        }
    }
}

// ---- Kernel W: W_out[512][1024] -> fragment-major fp8(e4m3) Wf (round-6 layout) ----
__global__ __launch_bounds__(256) void wt_kernel(const float* __restrict__ W,
                                                 unsigned char* __restrict__ Wf) {
    __shared__ float tile[32][33];
    int tid = threadIdx.x;
    int tx = tid & 31, ty = tid >> 5;  // 32x8
    int v0 = blockIdx.x * 32, k0 = blockIdx.y * 32;
#pragma unroll
    for (int i = 0; i < 4; ++i)
        tile[ty + i * 8][tx] = W[(size_t)(k0 + ty + i * 8) * V_ + v0 + tx];  // [k_loc][v_loc]
    __syncthreads();
    if (tid < 128) {
        int vl = tid >> 2, lg = tid & 3;
        int v  = v0 + vl;
        float x[8];
#pragma unroll
        for (int j = 0; j < 8; ++j) x[j] = tile[lg * 8 + j][vl];
        int lo = 0, hi = 0;
        lo = __builtin_amdgcn_cvt_pk_fp8_f32(x[0], x[1], lo, false);
        lo = __builtin_amdgcn_cvt_pk_fp8_f32(x[2], x[3], lo, true);
        hi = __builtin_amdgcn_cvt_pk_fp8_f32(x[4], x[5], hi, false);
        hi = __builtin_amdgcn_cvt_pk_fp8_f32(x[6], x[7], hi, true);
        int tl = v >> 4, ln = v & 15, kt = k0 >> 5;
        *(int2*)(Wf + tl * 8192 + kt * 512 + (lg * 16 + ln) * 8) = make_int2(lo, hi);
    }
}

// ---- Kernel H: precompute h = tanh(ep+pp) as fp8, PRE-SWIZZLED per 64-cell tile ------
// hG[tile][hb8(row, cb)] is the exact 32KB LDS image the joint copies linearly.
// Runs at full occupancy (no AGPR ballast) -> staging VALU off the joint's critical path.
__global__ __launch_bounds__(512) void hgen_kernel(const float* __restrict__ ep,
                                                   const float* __restrict__ pp,
                                                   unsigned char* __restrict__ hG) {
    int tid  = threadIdx.x;
    int tile = blockIdx.x;
    int row   = tid >> 3;
    int kslot = tid & 7;
    int cell  = tile * 64 + row;
    unsigned epRow = (unsigned)cell / 65u;
    int u = cell - (int)epRow * 65;
    int b = (int)(epRow >> 8);
    const float* epr = ep + (size_t)epRow * J_ + kslot * 64;
    const float* ppr = pp + (size_t)(b * UP1 + u) * J_ + kslot * 64;
    unsigned char* outb = hG + (size_t)tile * 32768;
#pragma unroll
    for (int c8 = 0; c8 < 8; ++c8) {
        float4 e0 = *(const float4*)(epr + c8 * 8);
        float4 e1 = *(const float4*)(epr + c8 * 8 + 4);
        float4 p0 = *(const float4*)(ppr + c8 * 8);
        float4 p1 = *(const float4*)(ppr + c8 * 8 + 4);
        float x[8] = {e0.x + p0.x, e0.y + p0.y, e0.z + p0.z, e0.w + p0.w,
                      e1.x + p1.x, e1.y + p1.y, e1.z + p1.z, e1.w + p1.w};
        float t[8];
#pragma unroll
        for (int j = 0; j < 8; ++j) {
            float e2 = __expf(2.f * x[j]);
            t[j] = 1.f - 2.f / (e2 + 1.f);
        }
        int lo = 0, hi = 0;
        lo = __builtin_amdgcn_cvt_pk_fp8_f32(t[0], t[1], lo, false);
        lo = __builtin_amdgcn_cvt_pk_fp8_f32(t[2], t[3], lo, true);
        hi = __builtin_amdgcn_cvt_pk_fp8_f32(t[4], t[5], hi, false);
        hi = __builtin_amdgcn_cvt_pk_fp8_f32(t[6], t[7], hi, true);
        unsigned cb = (unsigned)(kslot * 64 + c8 * 8);
        *(int2*)(outb + hb8((unsigned)row, cb)) = make_int2(lo, hi);
    }
}

// -------- Kernel B: fp8 MFMA joint. 64 cells x 1024 cols x K=512 per block (8 waves) ---
// PRE=true: h copied from hG (reg-staged linear, zero VALU). PRE=false: compute in-kernel.
template<bool PRE>
__global__ __launch_bounds__(512, 2) void joint_mfma(const float* __restrict__ ep,
                                                     const float* __restrict__ pp,
                                                     const unsigned char* __restrict__ hG,
                                                     const unsigned char* __restrict__ Wf,
                                                     const float* __restrict__ bout,
                                                     const int* __restrict__ labels,
                                                     const int* __restrict__ pblank,
                                                     float* __restrict__ blp,
                                                     float* __restrict__ llp) {
    __shared__ __align__(16) unsigned char hB[64 * 512];  // h[64][512] fp8, swizzled
    __shared__ float ps[8][64];
    __shared__ float lseA[64];

    int tid = threadIdx.x;
    int c0  = blockIdx.x * 64;
    int wc = tid >> 6, lane = tid & 63;
    int lg = lane >> 4, ln = lane & 15;

    // frag-major Wf as longs: index = (wc*8+ni)*1024 + kt*64 + lane
    const long* wfbL = (const long*)Wf + (wc << 13) + lane;

    long bf[3][8];
    long af[2][4];

    if (PRE) {
        // issue h tile loads (32KB, fully coalesced)
        int4 v[4];
        const int4* g = (const int4*)(hG + (size_t)blockIdx.x * 32768) + tid;
#pragma unroll
        for (int i = 0; i < 4; ++i) v[i] = g[i * 512];
        // overlap: issue bf prologue loads while h loads are in flight
#pragma unroll
        for (int ni = 0; ni < 8; ++ni) bf[0][ni] = wfbL[ni * 1024];
#pragma unroll
        for (int ni = 0; ni < 8; ++ni) bf[1][ni] = wfbL[ni * 1024 + 64];
        // write h into LDS (conflict-free linear b128 stores)
#pragma unroll
        for (int i = 0; i < 4; ++i) ((int4*)hB)[tid + i * 512] = v[i];
    } else {
        // ---- in-kernel staging (round-6-validated) ----
        int row   = tid >> 3;
        int kslot = tid & 7;
        int cell  = c0 + row;
        unsigned epRow = (unsigned)cell / 65u;
        int u = cell - (int)epRow * 65;
        int b = (int)(epRow >> 8);
        const float* epr = ep + (size_t)epRow * J_ + kslot * 64;
        const float* ppr = pp + (size_t)(b * UP1 + u) * J_ + kslot * 64;
#pragma unroll
        for (int c8 = 0; c8 < 8; ++c8) {
            float4 e0 = *(const float4*)(epr + c8 * 8);
            float4 e1 = *(const float4*)(epr + c8 * 8 + 4);
            float4 p0 = *(const float4*)(ppr + c8 * 8);
            float4 p1 = *(const float4*)(ppr + c8 * 8 + 4);
            float x[8] = {e0.x + p0.x, e0.y + p0.y, e0.z + p0.z, e0.w + p0.w,
                          e1.x + p1.x, e1.y + p1.y, e1.z + p1.z, e1.w + p1.w};
            float t[8];
#pragma unroll
            for (int j = 0; j < 8; ++j) {
                float e2 = __expf(2.f * x[j]);
                t[j] = 1.f - 2.f / (e2 + 1.f);
            }
            int lo = 0, hi = 0;
            lo = __builtin_amdgcn_cvt_pk_fp8_f32(t[0], t[1], lo, false);
            lo = __builtin_amdgcn_cvt_pk_fp8_f32(t[2], t[3], lo, true);
            hi = __builtin_amdgcn_cvt_pk_fp8_f32(t[4], t[5], hi, false);
            hi = __builtin_amdgcn_cvt_pk_fp8_f32(t[6], t[7], hi, true);
            unsigned cb = (unsigned)(kslot * 64 + c8 * 8);
            *(int2*)(hB + hb8((unsigned)row, cb)) = make_int2(lo, hi);
        }
#pragma unroll
        for (int ni = 0; ni < 8; ++ni) bf[0][ni] = wfbL[ni * 1024];
#pragma unroll
        for (int ni = 0; ni < 8; ++ni) bf[1][ni] = wfbL[ni * 1024 + 64];
    }
    __syncthreads();

    f32x4 acc[4][8] = {};

#pragma unroll
    for (int mi = 0; mi < 4; ++mi) {
        unsigned m  = (unsigned)(mi * 16 + ln);
        unsigned cb = (unsigned)(lg * 8);
        af[0][mi] = *(const long*)(hB + hb8(m, cb));
    }

#pragma unroll
    for (int kt = 0; kt < 16; ++kt) {
        const int cur3 = kt % 3;
        const int pf3  = (kt + 2) % 3;
        const int cur  = kt & 1, nxt = cur ^ 1;
#pragma unroll
        for (int ni = 0; ni < 8; ++ni) {
            if (kt < 14) bf[pf3][ni] = wfbL[ni * 1024 + (kt + 2) * 64];
            __builtin_amdgcn_s_setprio(1);
#pragma unroll
            for (int mi = 0; mi < 4; ++mi)
                acc[mi][ni] = __builtin_amdgcn_mfma_f32_16x16x32_fp8_fp8(
                    af[cur][mi], bf[cur3][ni], acc[mi][ni], 0, 0, 0);
            __builtin_amdgcn_s_setprio(0);
            if (ni == 3 && kt < 15) {
#pragma unroll
                for (int mi = 0; mi < 4; ++mi) {
                    unsigned m  = (unsigned)(mi * 16 + ln);
                    unsigned cb = (unsigned)((kt + 1) * 32 + lg * 8);
                    af[nxt][mi] = *(const long*)(hB + hb8(m, cb));
                }
            }
        }
    }

    // ---- epilogue: bias, exp-sum (|logits| small: no max needed), lse, gather ----
    float bo[8];
#pragma unroll
    for (int ni = 0; ni < 8; ++ni) bo[ni] = bout[(wc << 7) + (ni << 4) + ln];
#pragma unroll
    for (int mi = 0; mi < 4; ++mi)
#pragma unroll
        for (int ni = 0; ni < 8; ++ni)
#pragma unroll
            for (int r = 0; r < 4; ++r) acc[mi][ni][r] += bo[ni];

#pragma unroll
    for (int mi = 0; mi < 4; ++mi) {
#pragma unroll
        for (int r = 0; r < 4; ++r) {
            float s = 0.f;
#pragma unroll
            for (int ni = 0; ni < 8; ++ni) s += __expf(acc[mi][ni][r]);
            s += __shfl_xor(s, 1);
            s += __shfl_xor(s, 2);
            s += __shfl_xor(s, 4);
            s += __shfl_xor(s, 8);
            if (ln == 0) ps[wc][mi * 16 + lg * 4 + r] = s;
        }
    }
    __syncthreads();
    if (tid < 64) {
        float S = 0.f;
#pragma unroll
        for (int w2 = 0; w2 < 8; ++w2) S += ps[w2][tid];
        lseA[tid] = __logf(S);
    }
    __syncthreads();

    int blank = *pblank;
#pragma unroll
    for (int mi = 0; mi < 4; ++mi) {
#pragma unroll
        for (int r = 0; r < 4; ++r) {
            int row  = mi * 16 + lg * 4 + r;
            int cell = c0 + row;
            unsigned epRow = (unsigned)cell / 65u;
            int u = cell - (int)epRow * 65;
            int b = (int)(epRow >> 8);
            int lab = (u < U_) ? labels[(b << 6) + u] : -1;
            float lse = lseA[row];
#pragma unroll
            for (int ni = 0; ni < 8; ++ni) {
                int col  = (wc << 7) + (ni << 4) + ln;
                float lp = acc[mi][ni][r] - lse;
                if (col == blank) blp[cell] = lp;
                if (col == lab)   llp[(size_t)(((int)epRow << 6) + u)] = lp;
            }
        }
    }
}

// ------- Kernel C: alpha scan, log2-domain, DPP scans + prefetched loads ---------------
__global__ __launch_bounds__(512) void scan_kernel(const float* __restrict__ blp,
                                                   const float* __restrict__ llp,
                                                   const int* __restrict__ enc_lens,
                                                   const int* __restrict__ label_lens,
                                                   float* __restrict__ out) {
    __shared__ float lossArr[B_];
    const float K2  = 1.4426950408889634f;   // log2(e)
    const float LN2 = 0.6931471805599453f;
    int tid  = threadIdx.x;
    int b    = tid >> 6;
    int lane = tid & 63;
    int el = enc_lens[b];
    int ll = label_lens[b];
    float alpha   = (lane == 0) ? 0.f : LOG0;  // log2-domain
    float alpha64 = LOG0;
    const float* bb = &blp[(size_t)b * T_ * UP1];
    const float* lb = &llp[(size_t)b * T_ * U_];

    float bv_n   = bb[lane] * K2;
    float bv64_n = bb[64] * K2;
    float lv_n   = lb[lane] * K2;

    for (int t = 0; t < T_; ++t) {
        float bv = bv_n, bv64 = bv64_n, lv = lv_n;
        if (t + 1 < T_) {                       // prefetch next t (off critical chain)
            bv_n   = bb[(t + 1) * UP1 + lane] * K2;
            bv64_n = bb[(t + 1) * UP1 + 64] * K2;
            lv_n   = lb[(t + 1) * U_ + lane] * K2;
        }
        float P = wave_prefix_sum(lv);
        float L = dpps<0x111, 0xf>(P);
        float P15 = rdlane(P, 15), P31 = rdlane(P, 31), P47 = rdlane(P, 47);
        if (lane == 0)  L = 0.f;
        if (lane == 16) L = P15;
        if (lane == 32) L = P31;
        if (lane == 48) L = P47;
        float P63 = rdlane(P, 63);
        float x   = alpha + bv - L;
        float x64 = alpha64 + bv64 - P63;
        float M = fmaxf(wave_max_all(x), x64);
        float S = wave_prefix_sum(__builtin_amdgcn_exp2f(x - M));
        float S63 = rdlane(S, 63);
        float anew   = L + M + __builtin_amdgcn_logf(S);
        float anew64 = P63 + M +
                       __builtin_amdgcn_logf(S63 + __builtin_amdgcn_exp2f(x64 - M));
        if (t < el) {  // wave-uniform
            alpha   = anew;
            alpha64 = anew64;
        }
    }

    float term = bb[(el - 1) * UP1 + ll] * K2;
    int li = (ll < 64) ? ll : 63;
    float aU = __shfl(alpha, li);
    if (ll >= 64) aU = alpha64;
    if (lane == 0) lossArr[b] = -(aU + term) * LN2;
    __syncthreads();
    if (tid == 0) {
        float s = 0.f;
        for (int i = 0; i < B_; ++i) s += lossArr[i];
        out[0] = s / (float)B_;
    }
}

extern "C" void kernel_launch(void* const* d_in, const int* in_sizes, int n_in,
                              void* d_out, int out_size, void* d_ws, size_t ws_size,
                              hipStream_t stream) {
    (void)in_sizes; (void)n_in; (void)out_size;
    const float* enc        = (const float*)d_in[0];
    const float* pred       = (const float*)d_in[1];
    const float* W_enc      = (const float*)d_in[2];
    const float* W_pred     = (const float*)d_in[3];
    const float* b_joint    = (const float*)d_in[4];
    const float* W_out      = (const float*)d_in[5];
    const float* b_out      = (const float*)d_in[6];
    const int*   labels     = (const int*)d_in[7];
    const int*   enc_lens   = (const int*)d_in[8];
    const int*   label_lens = (const int*)d_in[9];
    const int*   blank_id   = (const int*)d_in[10];

    float* ep  = (float*)d_ws;                      // B*T*J   = 1,048,576 f
    float* pp  = ep  + (size_t)B_ * T_ * J_;        // B*65*J  =   266,240 f
    float* blp = pp  + (size_t)B_ * UP1 * J_;       // B*T*65  =   133,120 f
    float* llp = blp + (size_t)B_ * T_ * UP1;       // B*T*64  =   131,072 f
    unsigned char* Wf = (unsigned char*)(llp + (size_t)B_ * T_ * U_);  // 512KB frag fp8
    unsigned char* hG = Wf + (size_t)V_ * J_;       // NCELL*512 fp8 = 68.2 MB (optional)

    size_t need = (size_t)(hG - (unsigned char*)d_ws) + (size_t)NCELL * 512;
    bool pre = ws_size >= need;

    wt_kernel<<<dim3(V_ / 32, J_ / 32), dim3(256), 0, stream>>>(W_out, Wf);
    gemm_in<<<dim3((B_ * T_ + 63) / 64, J_ / 64), dim3(256), 0, stream>>>(
        enc, W_enc, b_joint, ep, B_ * T_);
    gemm_in<<<dim3((B_ * UP1 + 63) / 64, J_ / 64), dim3(256), 0, stream>>>(
        pred, W_pred, nullptr, pp, B_ * UP1);
    if (pre) {
        hgen_kernel<<<dim3(NCELL / 64), dim3(512), 0, stream>>>(ep, pp, hG);
        joint_mfma<true><<<dim3(NCELL / 64), dim3(512), 0, stream>>>(
            ep, pp, hG, Wf, b_out, labels, blank_id, blp, llp);
    } else {
        joint_mfma<false><<<dim3(NCELL / 64), dim3(512), 0, stream>>>(
            ep, pp, hG, Wf, b_out, labels, blank_id, blp, llp);
    }
    scan_kernel<<<dim3(1), dim3(512), 0, stream>>>(blp, llp, enc_lens, label_lens,
                                                   (float*)d_out);
}

// Round 11
// 340.569 us; speedup vs baseline: 3.1120x; 1.2984x over previous
//
#include <hip/hip_runtime.h>
#include <math.h>

#define B_   8
#define T_   256
#define U_   64
#define UP1  65
#define DE   640
#define J_   512
#define V_   1024
#define NCELL (B_ * T_ * UP1)
#define LOG0 -1e30f

typedef __attribute__((ext_vector_type(4))) float f32x4;

// ---------------- DPP wave64 scan/reduce helpers -------------------------------------
template<int CTRL, int RM>
__device__ __forceinline__ float dppz(float x) {
    return __builtin_bit_cast(float,
        __builtin_amdgcn_update_dpp(0, __builtin_bit_cast(int, x), CTRL, RM, 0xf, false));
}
template<int CTRL, int RM>
__device__ __forceinline__ float dpps(float x) {
    int xi = __builtin_bit_cast(int, x);
    return __builtin_bit_cast(float,
        __builtin_amdgcn_update_dpp(xi, xi, CTRL, RM, 0xf, false));
}
__device__ __forceinline__ float wave_prefix_sum(float v) {
    v += dppz<0x111, 0xf>(v);
    v += dppz<0x112, 0xf>(v);
    v += dppz<0x114, 0xf>(v);
    v += dppz<0x118, 0xf>(v);
    v += dppz<0x142, 0xa>(v);
    v += dppz<0x143, 0xc>(v);
    return v;
}
__device__ __forceinline__ float wave_max_all(float v) {
    v = fmaxf(v, dpps<0x111, 0xf>(v));
    v = fmaxf(v, dpps<0x112, 0xf>(v));
    v = fmaxf(v, dpps<0x114, 0xf>(v));
    v = fmaxf(v, dpps<0x118, 0xf>(v));
    v = fmaxf(v, dpps<0x142, 0xa>(v));
    v = fmaxf(v, dpps<0x143, 0xc>(v));
    return __builtin_bit_cast(float,
        __builtin_amdgcn_readlane(__builtin_bit_cast(int, v), 63));
}
__device__ __forceinline__ float rdlane(float v, int l) {
    return __builtin_bit_cast(float,
        __builtin_amdgcn_readlane(__builtin_bit_cast(int, v), l));
}

// LDS swizzle for fp8 hB: row m (512B rows), cb = column byte offset (8B granular).
__device__ __forceinline__ unsigned hb8(unsigned m, unsigned cb) {
    return m * 512u + (cb ^ ((m & 15u) << 3));
}

// ---------------- Kernel A: C[M x 512] = A[M x 640] * W[640 x 512] (+bias) -------------
__global__ __launch_bounds__(256) void gemm_in(const float* __restrict__ A,
                                               const float* __restrict__ W,
                                               const float* __restrict__ bias,
                                               float* __restrict__ C, int M) {
    __shared__ float As[16][64];
    __shared__ float Bs[16][64];
    int tid  = threadIdx.x;
    int row0 = blockIdx.x * 64;
    int col0 = blockIdx.y * 64;
    int tx = tid & 15, ty = tid >> 4;
    float acc[4][4] = {};
    int ar  = tid >> 2;
    int akq = tid & 3;
    int bkr = tid >> 4;
    int bcq = tid & 15;
    for (int k0 = 0; k0 < DE; k0 += 16) {
        float4 av = make_float4(0.f, 0.f, 0.f, 0.f);
        int arow = row0 + ar;
        if (arow < M) av = *(const float4*)&A[arow * DE + k0 + akq * 4];
        As[akq * 4 + 0][ar] = av.x;
        As[akq * 4 + 1][ar] = av.y;
        As[akq * 4 + 2][ar] = av.z;
        As[akq * 4 + 3][ar] = av.w;
        *(float4*)&Bs[bkr][bcq * 4] = *(const float4*)&W[(k0 + bkr) * J_ + col0 + bcq * 4];
        __syncthreads();
#pragma unroll
        for (int k = 0; k < 16; ++k) {
            float4 a4 = *(const float4*)&As[k][ty * 4];
            float4 b4 = *(const float4*)&Bs[k][tx * 4];
            float a[4] = {a4.x, a4.y, a4.z, a4.w};
            float b[4] = {b4.x, b4.y, b4.z, b4.w};
#pragma unroll
            for (int i = 0; i < 4; ++i)
#pragma unroll
                for (int j = 0; j < 4; ++j) acc[i][j] += a[i] * b[j];
        }
        __syncthreads();
    }
#pragma unroll
    for (int i = 0; i < 4; ++i) {
        int row = row0 + ty * 4 + i;
        if (row >= M) continue;
#pragma unroll
        for (int j = 0; j < 4; ++j) {
            int col = col0 + tx * 4 + j;
            float v = acc[i][j];
            if (bias) v += bias[col];
            C[row * J_ + col] = v;
        }
    }
}

// ---- Kernel W: W_out[512][1024] -> fragment-major fp8(e4m3) Wf (round-6 layout) ----
__global__ __launch_bounds__(256) void wt_kernel(const float* __restrict__ W,
                                                 unsigned char* __restrict__ Wf) {
    __shared__ float tile[32][33];
    int tid = threadIdx.x;
    int tx = tid & 31, ty = tid >> 5;  // 32x8
    int v0 = blockIdx.x * 32, k0 = blockIdx.y * 32;
#pragma unroll
    for (int i = 0; i < 4; ++i)
        tile[ty + i * 8][tx] = W[(size_t)(k0 + ty + i * 8) * V_ + v0 + tx];
    __syncthreads();
    if (tid < 128) {
        int vl = tid >> 2, lg = tid & 3;
        int v  = v0 + vl;
        float x[8];
#pragma unroll
        for (int j = 0; j < 8; ++j) x[j] = tile[lg * 8 + j][vl];
        int lo = 0, hi = 0;
        lo = __builtin_amdgcn_cvt_pk_fp8_f32(x[0], x[1], lo, false);
        lo = __builtin_amdgcn_cvt_pk_fp8_f32(x[2], x[3], lo, true);
        hi = __builtin_amdgcn_cvt_pk_fp8_f32(x[4], x[5], hi, false);
        hi = __builtin_amdgcn_cvt_pk_fp8_f32(x[6], x[7], hi, true);
        int tl = v >> 4, ln = v & 15, kt = k0 >> 5;
        *(int2*)(Wf + tl * 8192 + kt * 512 + (lg * 16 + ln) * 8) = make_int2(lo, hi);
    }
}

// ---- Kernel H: h = tanh(ep+pp) fp8, pre-swizzled, OUTPUT-LINEAR (coalesced writes) ---
// Output granule o holds source cols (o&511)^swz.. ; swizzle applied on READ side.
__global__ __launch_bounds__(512) void hgen_kernel(const float* __restrict__ ep,
                                                   const float* __restrict__ pp,
                                                   unsigned char* __restrict__ hG) {
    int tid  = threadIdx.x;
    int tile = blockIdx.x;
    unsigned char* outb = hG + (size_t)tile * 32768;
#pragma unroll
    for (int i = 0; i < 4; ++i) {
        int g   = tid + i * 512;          // 16B granule index, 0..2047
        int row = g >> 5;                 // 32 granules per 512B row
        int lin9 = (g & 31) * 16;         // 16B-aligned offset within row
        unsigned swz = ((unsigned)(row & 15)) << 3;
        int k0   = lin9 ^ (int)(swz & ~8u);   // 16B-aligned source column base
        int swap = row & 1;                   // halves swapped iff swz bit3 set
        int cell = tile * 64 + row;
        unsigned epRow = (unsigned)cell / 65u;
        int u = cell - (int)epRow * 65;
        int b = (int)(epRow >> 8);
        const float* epr = ep + (size_t)epRow * J_ + k0;
        const float* ppr = pp + (size_t)(b * UP1 + u) * J_ + k0;
        float t[16];
#pragma unroll
        for (int q = 0; q < 4; ++q) {
            float4 e = *(const float4*)(epr + q * 4);
            float4 p = *(const float4*)(ppr + q * 4);
            float xs[4] = {e.x + p.x, e.y + p.y, e.z + p.z, e.w + p.w};
#pragma unroll
            for (int j = 0; j < 4; ++j) {
                float e2 = __expf(2.f * xs[j]);
                t[q * 4 + j] = 1.f - 2.f / (e2 + 1.f);
            }
        }
        int a0 = 0, a1 = 0, b0 = 0, b1 = 0;
        a0 = __builtin_amdgcn_cvt_pk_fp8_f32(t[0], t[1], a0, false);
        a0 = __builtin_amdgcn_cvt_pk_fp8_f32(t[2], t[3], a0, true);
        a1 = __builtin_amdgcn_cvt_pk_fp8_f32(t[4], t[5], a1, false);
        a1 = __builtin_amdgcn_cvt_pk_fp8_f32(t[6], t[7], a1, true);
        b0 = __builtin_amdgcn_cvt_pk_fp8_f32(t[8], t[9], b0, false);
        b0 = __builtin_amdgcn_cvt_pk_fp8_f32(t[10], t[11], b0, true);
        b1 = __builtin_amdgcn_cvt_pk_fp8_f32(t[12], t[13], b1, false);
        b1 = __builtin_amdgcn_cvt_pk_fp8_f32(t[14], t[15], b1, true);
        int4 w = swap ? make_int4(b0, b1, a0, a1) : make_int4(a0, a1, b0, b1);
        *(int4*)(outb + g * 16) = w;     // fully coalesced
    }
}

// ---- Kernel B: fp8 MFMA joint, 4-way col-split, 256thr/4waves, 3 blocks/CU ----------
// blockIdx: bx>>2 = cell tile (64 cells), bx&3 = col quarter (256 cols).
// wave wc: cols bh*256 + wc*64; frag grid 4mi x 4ni; acc[4][4] = 64 AGPR.
__global__ __launch_bounds__(256, 3) void joint_mfma(const unsigned char* __restrict__ hG,
                                                     const unsigned char* __restrict__ Wf,
                                                     const float* __restrict__ bout,
                                                     const int* __restrict__ labels,
                                                     const int* __restrict__ pblank,
                                                     float* __restrict__ Spart,
                                                     float* __restrict__ blp,
                                                     float* __restrict__ llp) {
    __shared__ __align__(16) unsigned char hB[64 * 512];
    __shared__ float ps[4][64];

    int tid  = threadIdx.x;
    int bx   = blockIdx.x;
    int tile = bx >> 2;
    int bh   = bx & 3;
    int c0   = tile * 64;
    int wc = tid >> 6, lane = tid & 63;
    int lg = lane >> 4, ln = lane & 15;

    // frag-major Wf as longs: tile index bh*16 + wc*4 + ni
    const long* wfbL = (const long*)Wf + (((bh << 4) + (wc << 2)) << 10) + lane;

    long bf[3][4];
    long af[2][4];

    // stage: linear 32KB copy hG -> LDS, bf prologue overlapped
    {
        int4 v[8];
        const int4* g = (const int4*)(hG + (size_t)tile * 32768) + tid;
#pragma unroll
        for (int i = 0; i < 8; ++i) v[i] = g[i * 256];
#pragma unroll
        for (int ni = 0; ni < 4; ++ni) bf[0][ni] = wfbL[ni * 1024];
#pragma unroll
        for (int ni = 0; ni < 4; ++ni) bf[1][ni] = wfbL[ni * 1024 + 64];
#pragma unroll
        for (int i = 0; i < 8; ++i) ((int4*)hB)[tid + i * 256] = v[i];
    }
    __syncthreads();

    f32x4 acc[4][4] = {};
#pragma unroll
    for (int mi = 0; mi < 4; ++mi)
        af[0][mi] = *(const long*)(hB + hb8((unsigned)(mi * 16 + ln), (unsigned)(lg * 8)));

#pragma unroll
    for (int kt = 0; kt < 16; ++kt) {
        const int cur3 = kt % 3;
        const int pf3  = (kt + 2) % 3;
        const int cur  = kt & 1, nxt = cur ^ 1;
#pragma unroll
        for (int ni = 0; ni < 4; ++ni) {
            if (kt < 14) bf[pf3][ni] = wfbL[ni * 1024 + (kt + 2) * 64];
            __builtin_amdgcn_s_setprio(1);
#pragma unroll
            for (int mi = 0; mi < 4; ++mi)
                acc[mi][ni] = __builtin_amdgcn_mfma_f32_16x16x32_fp8_fp8(
                    af[cur][mi], bf[cur3][ni], acc[mi][ni], 0, 0, 0);
            __builtin_amdgcn_s_setprio(0);
            if (ni == 1 && kt < 15) {
#pragma unroll
                for (int mi = 0; mi < 4; ++mi) {
                    unsigned m  = (unsigned)(mi * 16 + ln);
                    unsigned cb = (unsigned)((kt + 1) * 32 + lg * 8);
                    af[nxt][mi] = *(const long*)(hB + hb8(m, cb));
                }
            }
        }
    }

    // ---- epilogue: bias, partial exp-sum over this quarter's 256 cols, raw gather ----
    float bo[4];
#pragma unroll
    for (int ni = 0; ni < 4; ++ni) bo[ni] = bout[(bh << 8) + (wc << 6) + (ni << 4) + ln];
#pragma unroll
    for (int mi = 0; mi < 4; ++mi)
#pragma unroll
        for (int ni = 0; ni < 4; ++ni)
#pragma unroll
            for (int r = 0; r < 4; ++r) acc[mi][ni][r] += bo[ni];

#pragma unroll
    for (int mi = 0; mi < 4; ++mi) {
#pragma unroll
        for (int r = 0; r < 4; ++r) {
            float s = 0.f;
#pragma unroll
            for (int ni = 0; ni < 4; ++ni) s += __expf(acc[mi][ni][r]);
            s += __shfl_xor(s, 1);
            s += __shfl_xor(s, 2);
            s += __shfl_xor(s, 4);
            s += __shfl_xor(s, 8);
            if (ln == 0) ps[wc][mi * 16 + lg * 4 + r] = s;
        }
    }
    __syncthreads();
    if (tid < 64) {
        float S = ps[0][tid] + ps[1][tid] + ps[2][tid] + ps[3][tid];
        Spart[(size_t)bh * NCELL + c0 + tid] = S;
    }

    int blank = *pblank;
#pragma unroll
    for (int mi = 0; mi < 4; ++mi) {
#pragma unroll
        for (int r = 0; r < 4; ++r) {
            int row  = mi * 16 + lg * 4 + r;
            int cell = c0 + row;
            unsigned epRow = (unsigned)cell / 65u;
            int u = cell - (int)epRow * 65;
            int b = (int)(epRow >> 8);
            int lab = (u < U_) ? labels[(b << 6) + u] : -1;
#pragma unroll
            for (int ni = 0; ni < 4; ++ni) {
                int col = (bh << 8) + (wc << 6) + (ni << 4) + ln;
                float lgt = acc[mi][ni][r];
                if (col == blank) blp[cell] = lgt;                            // raw
                if (col == lab)   llp[(size_t)(((int)epRow << 6) + u)] = lgt; // raw
            }
        }
    }
}

// ---- Pass 2: lse = log(S0+S1+S2+S3); subtract from raw blank/label logits ----
__global__ __launch_bounds__(256) void pass2_kernel(const float* __restrict__ Spart,
                                                    float* __restrict__ blp,
                                                    float* __restrict__ llp) {
    int idx = blockIdx.x * 256 + threadIdx.x;
    if (idx >= NCELL) return;
    float lse = __logf(Spart[idx] + Spart[NCELL + idx] +
                       Spart[2 * NCELL + idx] + Spart[3 * NCELL + idx]);
    blp[idx] -= lse;
    unsigned epRow = (unsigned)idx / 65u;
    int u = idx - (int)epRow * 65;
    if (u < U_) llp[(size_t)((epRow << 6) + u)] -= lse;
}

// ------- Kernel C: alpha scan, log2-domain, DPP scans + prefetched loads ---------------
__global__ __launch_bounds__(512) void scan_kernel(const float* __restrict__ blp,
                                                   const float* __restrict__ llp,
                                                   const int* __restrict__ enc_lens,
                                                   const int* __restrict__ label_lens,
                                                   float* __restrict__ out) {
    __shared__ float lossArr[B_];
    const float K2  = 1.4426950408889634f;
    const float LN2 = 0.6931471805599453f;
    int tid  = threadIdx.x;
    int b    = tid >> 6;
    int lane = tid & 63;
    int el = enc_lens[b];
    int ll = label_lens[b];
    float alpha   = (lane == 0) ? 0.f : LOG0;
    float alpha64 = LOG0;
    const float* bb = &blp[(size_t)b * T_ * UP1];
    const float* lb = &llp[(size_t)b * T_ * U_];

    float bv_n   = bb[lane] * K2;
    float bv64_n = bb[64] * K2;
    float lv_n   = lb[lane] * K2;

    for (int t = 0; t < T_; ++t) {
        float bv = bv_n, bv64 = bv64_n, lv = lv_n;
        if (t + 1 < T_) {
            bv_n   = bb[(t + 1) * UP1 + lane] * K2;
            bv64_n = bb[(t + 1) * UP1 + 64] * K2;
            lv_n   = lb[(t + 1) * U_ + lane] * K2;
        }
        float P = wave_prefix_sum(lv);
        float L = dpps<0x111, 0xf>(P);
        float P15 = rdlane(P, 15), P31 = rdlane(P, 31), P47 = rdlane(P, 47);
        if (lane == 0)  L = 0.f;
        if (lane == 16) L = P15;
        if (lane == 32) L = P31;
        if (lane == 48) L = P47;
        float P63 = rdlane(P, 63);
        float x   = alpha + bv - L;
        float x64 = alpha64 + bv64 - P63;
        float M = fmaxf(wave_max_all(x), x64);
        float S = wave_prefix_sum(__builtin_amdgcn_exp2f(x - M));
        float S63 = rdlane(S, 63);
        float anew   = L + M + __builtin_amdgcn_logf(S);
        float anew64 = P63 + M +
                       __builtin_amdgcn_logf(S63 + __builtin_amdgcn_exp2f(x64 - M));
        if (t < el) {
            alpha   = anew;
            alpha64 = anew64;
        }
    }

    float term = bb[(el - 1) * UP1 + ll] * K2;
    int li = (ll < 64) ? ll : 63;
    float aU = __shfl(alpha, li);
    if (ll >= 64) aU = alpha64;
    if (lane == 0) lossArr[b] = -(aU + term) * LN2;
    __syncthreads();
    if (tid == 0) {
        float s = 0.f;
        for (int i = 0; i < B_; ++i) s += lossArr[i];
        out[0] = s / (float)B_;
    }
}

extern "C" void kernel_launch(void* const* d_in, const int* in_sizes, int n_in,
                              void* d_out, int out_size, void* d_ws, size_t ws_size,
                              hipStream_t stream) {
    (void)in_sizes; (void)n_in; (void)out_size; (void)ws_size;
    const float* enc        = (const float*)d_in[0];
    const float* pred       = (const float*)d_in[1];
    const float* W_enc      = (const float*)d_in[2];
    const float* W_pred     = (const float*)d_in[3];
    const float* b_joint    = (const float*)d_in[4];
    const float* W_out      = (const float*)d_in[5];
    const float* b_out      = (const float*)d_in[6];
    const int*   labels     = (const int*)d_in[7];
    const int*   enc_lens   = (const int*)d_in[8];
    const int*   label_lens = (const int*)d_in[9];
    const int*   blank_id   = (const int*)d_in[10];

    float* ep  = (float*)d_ws;                      // B*T*J   = 1,048,576 f
    float* pp  = ep  + (size_t)B_ * T_ * J_;        // B*65*J  =   266,240 f
    float* blp = pp  + (size_t)B_ * UP1 * J_;       // B*T*65  =   133,120 f
    float* llp = blp + (size_t)B_ * T_ * UP1;       // B*T*64  =   131,072 f
    unsigned char* Wf = (unsigned char*)(llp + (size_t)B_ * T_ * U_);  // 512KB frag fp8
    float* Spart = (float*)(Wf + (size_t)V_ * J_);  // 4 * NCELL f32
    unsigned char* hG = (unsigned char*)(Spart + (size_t)4 * NCELL);   // NCELL*512 fp8

    wt_kernel<<<dim3(V_ / 32, J_ / 32), dim3(256), 0, stream>>>(W_out, Wf);
    gemm_in<<<dim3((B_ * T_ + 63) / 64, J_ / 64), dim3(256), 0, stream>>>(
        enc, W_enc, b_joint, ep, B_ * T_);
    gemm_in<<<dim3((B_ * UP1 + 63) / 64, J_ / 64), dim3(256), 0, stream>>>(
        pred, W_pred, nullptr, pp, B_ * UP1);
    hgen_kernel<<<dim3(NCELL / 64), dim3(512), 0, stream>>>(ep, pp, hG);
    joint_mfma<<<dim3(NCELL / 64 * 4), dim3(256), 0, stream>>>(
        hG, Wf, b_out, labels, blank_id, Spart, blp, llp);
    pass2_kernel<<<dim3((NCELL + 255) / 256), dim3(256), 0, stream>>>(Spart, blp, llp);
    scan_kernel<<<dim3(1), dim3(512), 0, stream>>>(blp, llp, enc_lens, label_lens,
                                                   (float*)d_out);
}